// Round 7
// baseline (74.146 us; speedup 1.0000x reference)
//
#include <hip/hip_runtime.h>
#include <math.h>

#define N_PTS 16384
#define D_DIM 128
#define C_CLS 10
#define K_MIX 16
#define HB    64                      // sort blocks, 256 pts each
#define BPC   52                      // main blocks per class
#define GRID3 (C_CLS * BPC)           // 520 main blocks
#define CPAD  2048                    // padded per-class region in idxPad

constexpr float EPSF   = 1.1920928955078125e-07f;  // np.finfo(float32).eps
constexpr float LOG2PI = 1.8378770664093453f;
constexpr float LN2F   = 0.6931471805599453f;

__device__ __forceinline__ float softplusf(float x) {
    if (x > 20.f)  return x;
    if (x < -20.f) return expf(x);
    return log1pf(expf(x));
}
__device__ __forceinline__ float ndtrf(float x) {
    return 0.5f * erfcf(-x * 0.70710678118654752440f);
}

// ---------------------------------------------------------------------------
// K1: self-contained deterministic class-partition. Block h:
//   A) counts classes in y[0 .. h*256) (int4 loads, 4 waves split the range)
//   B) ranks its own 256 points (ballot, round-6 proven pattern)
//   scatter: idxPad[c*CPAD + prefix + rank] = n. Block 63 writes counts[c].
// No cross-block dependencies.
// ---------------------------------------------------------------------------
__global__ __launch_bounds__(256) void k_sort(
    const int* __restrict__ y, int* __restrict__ idxPad,
    int* __restrict__ counts) {
    const int h = blockIdx.x, t = threadIdx.x;
    const int w = t >> 6, lane = t & 63;
    __shared__ int sPre4[4][C_CLS];
    __shared__ int sPre[C_CLS];
    __shared__ int wcnt[4][C_CLS];
    __shared__ int wbase[4][C_CLS];

    // A: prefix counts; wave w handles 256-pt chunks w, w+4, ...
    int ccnt[C_CLS];
    #pragma unroll
    for (int i = 0; i < C_CLS; ++i) ccnt[i] = 0;
    for (int ch = w; ch < h; ch += 4) {
        int4 v = *reinterpret_cast<const int4*>(y + ch * 256 + lane * 4);
        #pragma unroll
        for (int cc = 0; cc < C_CLS; ++cc)
            ccnt[cc] += (v.x == cc) + (v.y == cc) + (v.z == cc) + (v.w == cc);
    }
    #pragma unroll
    for (int cc = 0; cc < C_CLS; ++cc) {
        int s = ccnt[cc];
        #pragma unroll
        for (int o = 1; o < 64; o <<= 1) s += __shfl_xor(s, o);
        if (lane == 0) sPre4[w][cc] = s;
    }
    __syncthreads();
    if (t < C_CLS) sPre[t] = sPre4[0][t] + sPre4[1][t] + sPre4[2][t] + sPre4[3][t];
    __syncthreads();

    // B: rank own chunk (stable within block; blocks are naturally ordered)
    int n = h * 256 + t;
    int c = y[n];
    int rank = 0;
    #pragma unroll
    for (int cc = 0; cc < C_CLS; ++cc) {
        unsigned long long m = __ballot(c == cc);
        if (c == cc) rank = __popcll(m & ((1ull << lane) - 1ull));
        if (lane == 0) wcnt[w][cc] = __popcll(m);
    }
    __syncthreads();
    if (t < 4 * C_CLS) {
        int ww = t / C_CLS, cc = t % C_CLS;
        int s = sPre[cc];
        for (int w2 = 0; w2 < ww; ++w2) s += wcnt[w2][cc];
        wbase[ww][cc] = s;
    }
    __syncthreads();
    idxPad[c * CPAD + wbase[w][c] + rank] = n;

    if (h == HB - 1 && t < C_CLS)
        counts[t] = sPre[t] + wcnt[0][t] + wcnt[1][t] + wcnt[2][t] + wcnt[3][t];
}

// ---------------------------------------------------------------------------
// K2: main. Block = (class c, stripe j). Wave = 16 k-lanes x 4 dc-groups.
// Per block: params (a=is^2, b=2 mu is^2) built into registers from raw
// mu/sigma; Ack + lse computed in-block (no prep kernel). Batch loop: stage
// 16 X rows into LDS with 512 parallel coalesced float4 loads (stride-36
// segments -> conflict-free b128 reads), compute from LDS. No per-point
// shuffles. Last block (wrapping done-counter) does the final reduce.
// ---------------------------------------------------------------------------
__global__ __launch_bounds__(256) void k_main(
    const float* __restrict__ X, const float* __restrict__ resp,
    const float* __restrict__ mu, const float* __restrict__ lower,
    const float* __restrict__ upper, const float* __restrict__ sigma,
    const float* __restrict__ logits, const float* __restrict__ etap,
    const int* __restrict__ idxPad, const int* __restrict__ counts,
    float* __restrict__ partials, unsigned int* __restrict__ done,
    float* __restrict__ out) {
    const int b = blockIdx.x, t = threadIdx.x;
    const int w = t >> 6, lane = t & 63;
    const int k = lane & 15, dc = lane >> 4;
    const int d0 = dc * 32;
    const int c = b / BPC, j = b % BPC;

    __shared__ float xs[16][144];     // 16 rows, 4 segments of 32 @ stride 36
    __shared__ int   sIdx[16];
    __shared__ float zW[4][16];
    __shared__ float sAck[16];
    __shared__ float sLog[16];
    __shared__ float sW[4];
    __shared__ int   sLast;

    // ---- register params + per-k logsc / mu2 partials ----------------------
    const size_t pbase = ((size_t)(c * K_MIX + k)) * D_DIM + d0;
    float a_[32], b_[32];
    float logsc = 0.f, mu2 = 0.f;
    #pragma unroll
    for (int i4 = 0; i4 < 8; ++i4) {
        float4 mv = *reinterpret_cast<const float4*>(mu    + pbase + i4 * 4);
        float4 sv = *reinterpret_cast<const float4*>(sigma + pbase + i4 * 4);
        float m4[4] = {mv.x, mv.y, mv.z, mv.w};
        float s4[4] = {sv.x, sv.y, sv.z, sv.w};
        #pragma unroll
        for (int q = 0; q < 4; ++q) {
            int i = i4 * 4 + q;
            float sc = EPSF + softplusf(s4[q]);
            float is = 1.f / sc;
            a_[i] = is * is;
            b_[i] = 2.f * m4[q] * is * is;
            logsc += logf(sc);
            mu2   += m4[q] * m4[q] * is * is;
        }
    }
    // z-product: wave w covers dims d0 + w*8 .. +8 for this lane's k
    {
        float zp = 1.f;
        const size_t zb = pbase + w * 8;
        #pragma unroll
        for (int i4 = 0; i4 < 2; ++i4) {
            float4 mv = *reinterpret_cast<const float4*>(mu    + zb + i4 * 4);
            float4 sv = *reinterpret_cast<const float4*>(sigma + zb + i4 * 4);
            float4 lv = *reinterpret_cast<const float4*>(lower + zb + i4 * 4);
            float4 uv = *reinterpret_cast<const float4*>(upper + zb + i4 * 4);
            float m4[4] = {mv.x, mv.y, mv.z, mv.w};
            float s4[4] = {sv.x, sv.y, sv.z, sv.w};
            float l4[4] = {lv.x, lv.y, lv.z, lv.w};
            float u4[4] = {uv.x, uv.y, uv.z, uv.w};
            #pragma unroll
            for (int q = 0; q < 4; ++q) {
                float sc = EPSF + softplusf(s4[q]);
                float is = 1.f / sc;
                zp *= ndtrf((u4[q] - m4[q]) * is) - ndtrf((l4[q] - m4[q]) * is);
            }
        }
        zp *= __shfl_xor(zp, 16);
        zp *= __shfl_xor(zp, 32);
        if (lane < 16) zW[w][lane] = zp;
    }
    if (t < K_MIX) sLog[t] = logits[c * K_MIX + t];
    // full-D sums (over dc groups) for this lane's k
    logsc += __shfl_xor(logsc, 16); logsc += __shfl_xor(logsc, 32);
    mu2   += __shfl_xor(mu2, 16);   mu2   += __shfl_xor(mu2, 32);
    __syncthreads();
    if (w == 0 && lane < 16) {
        float z = zW[0][lane] * zW[1][lane] * zW[2][lane] * zW[3][lane];
        sAck[lane] = -logf(z + EPSF) - logsc
                   - 0.5f * (float)D_DIM * LOG2PI - 0.5f * mu2;
    }
    __syncthreads();

    // lse over the 16 logits (redundant per thread, trivial)
    float mx = sLog[0];
    #pragma unroll
    for (int q = 1; q < 16; ++q) mx = fmaxf(mx, sLog[q]);
    float se = 0.f;
    #pragma unroll
    for (int q = 0; q < 16; ++q) se += expf(sLog[q] - mx);
    float lse = mx + logf(se);

    const float eta = etap[0];
    const float lpconst = -2.f * (float)D_DIM * LN2F;
    const float ckk = sLog[k] - lse + sAck[k];
    const int   cnt = counts[c];
    const float inv = (cnt > 0) ? 1.f / ((float)cnt * (float)K_MIX) : 0.f;
    const float ck4 = 0.25f * (ckk + (eta == 0.f ? lpconst : 0.f));

    // ---- batch loop: stage 16 rows -> LDS, compute from LDS ----------------
    float wsum = 0.f;
    const int base0 = c * CPAD;
    for (int bi = j; bi * 16 < cnt; bi += BPC) {
        int p0 = bi * 16;
        int bn = cnt - p0; if (bn > 16) bn = 16;
        __syncthreads();                       // xs/sIdx reuse guard
        if (t < 16) sIdx[t] = idxPad[base0 + p0 + ((t < bn) ? t : 0)];
        __syncthreads();
        #pragma unroll
        for (int ps = 0; ps < 2; ++ps) {
            int row = ps * 8 + (t >> 5);
            int s   = t & 31;
            if (row < bn) {
                float4 v = *reinterpret_cast<const float4*>(
                    X + (size_t)sIdx[row] * D_DIM + s * 4);
                int o = (s >> 3) * 36 + (s & 7) * 4;
                *reinterpret_cast<float4*>(&xs[row][o]) = v;
            }
        }
        __syncthreads();
        #pragma unroll
        for (int pi = 0; pi < 4; ++pi) {
            int pt = w * 4 + pi;
            if (pt >= bn) break;
            int n = sIdx[pt];
            float r = resp[((size_t)c * N_PTS + n) * K_MIX + k];
            const float* xrow = &xs[pt][dc * 36];
            float acc = 0.f;
            #pragma unroll
            for (int q = 0; q < 8; ++q) {
                float4 xv = *reinterpret_cast<const float4*>(xrow + q * 4);
                acc = fmaf(xv.x, fmaf(a_[q*4+0], xv.x, -b_[q*4+0]), acc);
                acc = fmaf(xv.y, fmaf(a_[q*4+1], xv.y, -b_[q*4+1]), acc);
                acc = fmaf(xv.z, fmaf(a_[q*4+2], xv.z, -b_[q*4+2]), acc);
                acc = fmaf(xv.w, fmaf(a_[q*4+3], xv.w, -b_[q*4+3]), acc);
            }
            if (eta == 0.f) {
                wsum = fmaf(r, fmaf(-0.5f, acc, ck4), wsum);
            } else {
                float lpp = 0.f;
                #pragma unroll
                for (int q = 0; q < 8; ++q) {
                    float4 xv = *reinterpret_cast<const float4*>(xrow + q * 4);
                    float4 lv = *reinterpret_cast<const float4*>(lower + pbase + q * 4);
                    float4 uv = *reinterpret_cast<const float4*>(upper + pbase + q * 4);
                    float x4[4] = {xv.x, xv.y, xv.z, xv.w};
                    float l4[4] = {lv.x, lv.y, lv.z, lv.w};
                    float u4[4] = {uv.x, uv.y, uv.z, uv.w};
                    #pragma unroll
                    for (int qq = 0; qq < 4; ++qq)
                        lpp -= softplusf(-eta * (x4[qq] - l4[qq]))
                             + softplusf(-eta * (u4[qq] - x4[qq]));
                }
                wsum = fmaf(r, fmaf(-0.5f, acc, ck4 + lpp), wsum);
            }
        }
    }
    wsum *= inv;

    // ---- one butterfly, block combine, last-block final reduce -------------
    #pragma unroll
    for (int o = 1; o < 64; o <<= 1) wsum += __shfl_xor(wsum, o);
    if (lane == 0) sW[w] = wsum;
    __syncthreads();
    if (t == 0) {
        partials[b] = sW[0] + sW[1] + sW[2] + sW[3];
        __threadfence();
        unsigned int prev = __hip_atomic_fetch_add(done, 1u, __ATOMIC_ACQ_REL,
                                                   __HIP_MEMORY_SCOPE_AGENT);
        sLast = (((prev + 1u) % (unsigned int)GRID3) == 0u);
    }
    __syncthreads();

    if (sLast) {
        __threadfence();
        __shared__ float red[256];
        float s = partials[t];
        s += partials[t + 256];                 // 256..511 < 520
        if (t + 512 < GRID3) s += partials[t + 512];
        red[t] = s;
        __syncthreads();
        for (int o = 128; o > 0; o >>= 1) {
            if (t < o) red[t] += red[t + o];
            __syncthreads();
        }
        if (t == 0) out[0] = -red[0];
    }
}

// ---------------------------------------------------------------------------
extern "C" void kernel_launch(void* const* d_in, const int* in_sizes, int n_in,
                              void* d_out, int out_size, void* d_ws, size_t ws_size,
                              hipStream_t stream) {
    const float* X      = (const float*)d_in[0];
    const int*   y      = (const int*)  d_in[1];
    const float* resp   = (const float*)d_in[2];
    const float* mu     = (const float*)d_in[3];
    const float* lower  = (const float*)d_in[4];
    const float* upper  = (const float*)d_in[5];
    const float* sigma  = (const float*)d_in[6];
    const float* logits = (const float*)d_in[7];
    const float* eta    = (const float*)d_in[8];
    float* out = (float*)d_out;

    char* ws = (char*)d_ws;
    size_t off = 256;                 // first 256 B: wrapping done counter
    auto alloc = [&](size_t bytes) {
        void* p = ws + off;
        off += (bytes + 255) & ~size_t(255);
        return p;
    };
    unsigned int* done   = (unsigned int*)ws;
    int*   idxPad   = (int*)  alloc((size_t)C_CLS * CPAD * sizeof(int));
    int*   counts   = (int*)  alloc(C_CLS * sizeof(int));
    float* partials = (float*)alloc(GRID3 * sizeof(float));

    k_sort<<<HB, 256, 0, stream>>>(y, idxPad, counts);
    k_main<<<GRID3, 256, 0, stream>>>(X, resp, mu, lower, upper, sigma,
                                      logits, eta, idxPad, counts,
                                      partials, done, out);
}

// Round 8
// 73.485 us; speedup vs baseline: 1.0090x; 1.0090x over previous
//
#include <hip/hip_runtime.h>
#include <math.h>

#define N_PTS 16384
#define D_DIM 128
#define C_CLS 10
#define K_MIX 16
#define HB    64                      // histogram/scatter blocks (256 pts each)
#define GRID3 (N_PTS / 16)            // 1024 main blocks, 16 points each

constexpr float EPSF   = 1.1920928955078125e-07f;  // np.finfo(float32).eps
constexpr float LOG2PI = 1.8378770664093453f;
constexpr float LN2F   = 0.6931471805599453f;

__device__ __forceinline__ float softplusf(float x) {
    if (x > 20.f)  return x;
    if (x < -20.f) return expf(x);
    return log1pf(expf(x));
}
__device__ __forceinline__ float ndtrf(float x) {
    return 0.5f * erfcf(-x * 0.70710678118654752440f);
}

// ---------------------------------------------------------------------------
// K1 (round-2 proven, verbatim): blocks [0,160): per-(c,k) params ->
// abT(float2 {is^2, 2 mu is^2})[c][d][k], loT/upT[c][d][k], Ack[c*K+k]
// (-log_norm - sum log sc - 0.5 D LOG2PI - 0.5 sum mu^2 is^2).
// blocks [160,224): per-256-pt class histogram -> blockCnt[h][c].
// ---------------------------------------------------------------------------
__global__ __launch_bounds__(256) void k_prep(
    const float* __restrict__ mu, const float* __restrict__ lower,
    const float* __restrict__ upper, const float* __restrict__ sigma,
    const int* __restrict__ y,
    float2* __restrict__ abT, float* __restrict__ loT, float* __restrict__ upT,
    float* __restrict__ Ack, int* __restrict__ blockCnt) {
    int b = blockIdx.x, t = threadIdx.x;
    if (b < C_CLS * K_MIX) {
        int c = b / K_MIX, k = b % K_MIX;
        __shared__ float rs0[256], rs1[256], rp[256];
        float logsc = 0.f, mu2 = 0.f, zz = 1.f;
        if (t < D_DIM) {
            int gi = b * D_DIM + t;
            float m = mu[gi], lo = lower[gi], up = upper[gi], sg = sigma[gi];
            float sc = EPSF + softplusf(sg);
            float is = 1.f / sc;
            int ti = (c * D_DIM + t) * K_MIX + k;
            abT[ti] = make_float2(is * is, 2.f * m * is * is);
            loT[ti] = lo; upT[ti] = up;
            logsc = logf(sc);
            mu2   = m * m * is * is;
            zz    = ndtrf((up - m) * is) - ndtrf((lo - m) * is);
        }
        rs0[t] = logsc; rs1[t] = mu2; rp[t] = zz;
        __syncthreads();
        for (int off = 128; off > 0; off >>= 1) {
            if (t < off) { rs0[t] += rs0[t+off]; rs1[t] += rs1[t+off]; rp[t] *= rp[t+off]; }
            __syncthreads();
        }
        if (t == 0) {
            float log_norm = logf(rp[0] + EPSF);
            Ack[b] = -log_norm - rs0[0] - 0.5f * (float)D_DIM * LOG2PI - 0.5f * rs1[0];
        }
    } else {
        int h = b - C_CLS * K_MIX;
        __shared__ int hist[C_CLS];
        if (t < C_CLS) hist[t] = 0;
        __syncthreads();
        int c = y[h * 256 + t];
        int lane = t & 63;
        for (int cc = 0; cc < C_CLS; ++cc) {
            unsigned long long m = __ballot(c == cc);
            if (lane == 0 && m) atomicAdd(&hist[cc], __popcll(m));
        }
        __syncthreads();
        if (t < C_CLS) blockCnt[h * C_CLS + t] = hist[t];
    }
}

// ---------------------------------------------------------------------------
// K2 (round-2 proven, verbatim + done-counter zeroing): stable counting-sort
// scatter -> idxSorted; block 0 also writes classOff / invden / const_ck.
// ---------------------------------------------------------------------------
__global__ __launch_bounds__(256) void k_scatter(
    const int* __restrict__ y, const int* __restrict__ blockCnt,
    const float* __restrict__ logits, const float* __restrict__ Ack,
    int* __restrict__ idxSorted, int* __restrict__ classOff,
    float* __restrict__ invden, float* __restrict__ const_ck,
    int* __restrict__ done) {
    __shared__ int sCnt[HB * C_CLS];
    __shared__ int sOff[C_CLS + 1];
    __shared__ int sMyOff[C_CLS];
    __shared__ int wcnt[4][C_CLS];
    __shared__ int wbase[4][C_CLS];
    int h = blockIdx.x, t = threadIdx.x;
    if (h == 0 && t == 0) *done = 0;            // init last-block counter
    for (int i = t; i < HB * C_CLS; i += 256) sCnt[i] = blockCnt[i];
    __syncthreads();
    if (t == 0) {
        int acc = 0;
        for (int c = 0; c < C_CLS; ++c) {
            sOff[c] = acc;
            int s = 0;
            for (int hh = 0; hh < HB; ++hh) s += sCnt[hh * C_CLS + c];
            acc += s;
        }
        sOff[C_CLS] = acc;
    }
    __syncthreads();
    if (t < C_CLS) {
        int s = sOff[t];
        for (int hh = 0; hh < h; ++hh) s += sCnt[hh * C_CLS + t];
        sMyOff[t] = s;
    }
    __syncthreads();
    int n = h * 256 + t;
    int c = y[n];
    int w = t >> 6, lane = t & 63;
    int rank = 0;
    for (int cc = 0; cc < C_CLS; ++cc) {
        unsigned long long m = __ballot(c == cc);
        if (c == cc) rank = __popcll(m & ((1ull << lane) - 1ull));
        if (lane == 0) wcnt[w][cc] = __popcll(m);
    }
    __syncthreads();
    if (t < 4 * C_CLS) {
        int ww = t / C_CLS, cc = t % C_CLS;
        int s = sMyOff[cc];
        for (int w2 = 0; w2 < ww; ++w2) s += wcnt[w2][cc];
        wbase[ww][cc] = s;
    }
    __syncthreads();
    idxSorted[wbase[w][c] + rank] = n;

    if (h == 0) {
        __shared__ float lse[C_CLS];
        if (t < C_CLS) {
            float mx = -1e30f;
            for (int k = 0; k < K_MIX; ++k) mx = fmaxf(mx, logits[t * K_MIX + k]);
            float se = 0.f;
            for (int k = 0; k < K_MIX; ++k) se += expf(logits[t * K_MIX + k] - mx);
            lse[t] = mx + logf(se);
            int cnt = sOff[t + 1] - sOff[t];
            invden[t] = (cnt > 0) ? 1.f / ((float)cnt * (float)K_MIX) : 0.f;
        }
        if (t < C_CLS + 1) classOff[t] = sOff[t];
        __syncthreads();
        if (t < C_CLS * K_MIX) const_ck[t] = logits[t] - lse[t / K_MIX] + Ack[t];
    }
}

// ---------------------------------------------------------------------------
// K3: main. 1024 blocks x 256 threads; thread = (nl, k); 16 sorted points per
// block staged to LDS (coalesced float4, round-1 proven). Per-thread 128-d
// loop streams abT[c][d][k] float2 with 8 loads in flight (class-uniform
// waves -> one 128B L2 line per d per wave). k-shuffle reduce (round-1),
// last-block final reduce with K2-initialized done counter (round-5).
// ---------------------------------------------------------------------------
__global__ __launch_bounds__(256) void k_main(
    const float* __restrict__ X, const int* __restrict__ y,
    const float* __restrict__ resp,
    const float2* __restrict__ abT, const float* __restrict__ loT,
    const float* __restrict__ upT, const float* __restrict__ const_ck,
    const float* __restrict__ invden, const int* __restrict__ idxSorted,
    const float* __restrict__ etap,
    float* __restrict__ partials, int* __restrict__ done,
    float* __restrict__ out) {
    const int b = blockIdx.x, t = threadIdx.x;
    const int k = t & 15, nl = t >> 4;
    __shared__ float xs[16][132];
    __shared__ int   sIdx[16];
    __shared__ int   sC[16];
    __shared__ float sums[16];
    __shared__ int   sLast;

    if (t < 16) {
        int n = idxSorted[b * 16 + t];
        sIdx[t] = n;
        sC[t]   = y[n];
    }
    __syncthreads();
    #pragma unroll
    for (int i = 0; i < 2; ++i) {
        int jj = t * 2 + i;                // 0..511 float4 slots
        int r  = jj >> 5, c4 = jj & 31;
        float4 v = *reinterpret_cast<const float4*>(
            X + (size_t)sIdx[r] * D_DIM + c4 * 4);
        xs[r][c4 * 4 + 0] = v.x; xs[r][c4 * 4 + 1] = v.y;
        xs[r][c4 * 4 + 2] = v.z; xs[r][c4 * 4 + 3] = v.w;
    }
    __syncthreads();

    const int n = sIdx[nl];
    const int c = sC[nl];
    const float eta = etap[0];
    const float2* ap = abT + (size_t)c * (D_DIM * K_MIX) + k;

    float acc = 0.f;
    for (int d0 = 0; d0 < D_DIM; d0 += 8) {
        float2 pv[8];
        float  xv[8];
        #pragma unroll
        for (int q = 0; q < 8; ++q) pv[q] = ap[(size_t)(d0 + q) * K_MIX];
        #pragma unroll
        for (int q = 0; q < 8; ++q) xv[q] = xs[nl][d0 + q];
        #pragma unroll
        for (int q = 0; q < 8; ++q)
            acc = fmaf(xv[q], fmaf(pv[q].x, xv[q], -pv[q].y), acc);
    }

    float lp;
    if (eta == 0.f) {
        lp = -2.f * (float)D_DIM * LN2F;
    } else {
        lp = 0.f;
        const float* lo = loT + (size_t)c * (D_DIM * K_MIX) + k;
        const float* up = upT + (size_t)c * (D_DIM * K_MIX) + k;
        for (int d0 = 0; d0 < D_DIM; d0 += 8) {
            float lv[8], uv[8], xv[8];
            #pragma unroll
            for (int q = 0; q < 8; ++q) lv[q] = lo[(size_t)(d0 + q) * K_MIX];
            #pragma unroll
            for (int q = 0; q < 8; ++q) uv[q] = up[(size_t)(d0 + q) * K_MIX];
            #pragma unroll
            for (int q = 0; q < 8; ++q) xv[q] = xs[nl][d0 + q];
            #pragma unroll
            for (int q = 0; q < 8; ++q)
                lp -= softplusf(-eta * (xv[q] - lv[q]))
                    + softplusf(-eta * (uv[q] - xv[q]));
        }
    }

    float r_ = resp[((size_t)c * N_PTS + n) * K_MIX + k];
    float v  = r_ * (const_ck[c * K_MIX + k] + lp - 0.5f * acc) * invden[c];

    // sum over the 16 k-lanes of this n (fixed-order tree; round-1 proven)
    v += __shfl_xor(v, 1);
    v += __shfl_xor(v, 2);
    v += __shfl_xor(v, 4);
    v += __shfl_xor(v, 8);
    if (k == 0) sums[nl] = v;
    __syncthreads();
    if (t == 0) {
        float s = 0.f;
        #pragma unroll
        for (int i = 0; i < 16; ++i) s += sums[i];
        partials[b] = s;
        __threadfence();
        int prev = __hip_atomic_fetch_add(done, 1, __ATOMIC_ACQ_REL,
                                          __HIP_MEMORY_SCOPE_AGENT);
        sLast = (prev == GRID3 - 1);
    }
    __syncthreads();

    if (sLast) {
        __threadfence();
        __shared__ float red[256];
        float s = partials[t] + partials[t + 256]
                + partials[t + 512] + partials[t + 768];
        red[t] = s;
        __syncthreads();
        for (int o = 128; o > 0; o >>= 1) {
            if (t < o) red[t] += red[t + o];
            __syncthreads();
        }
        if (t == 0) out[0] = -red[0];
    }
}

// ---------------------------------------------------------------------------
extern "C" void kernel_launch(void* const* d_in, const int* in_sizes, int n_in,
                              void* d_out, int out_size, void* d_ws, size_t ws_size,
                              hipStream_t stream) {
    const float* X      = (const float*)d_in[0];
    const int*   y      = (const int*)  d_in[1];
    const float* resp   = (const float*)d_in[2];
    const float* mu     = (const float*)d_in[3];
    const float* lower  = (const float*)d_in[4];
    const float* upper  = (const float*)d_in[5];
    const float* sigma  = (const float*)d_in[6];
    const float* logits = (const float*)d_in[7];
    const float* eta    = (const float*)d_in[8];
    float* out = (float*)d_out;

    char* ws = (char*)d_ws;
    size_t off = 256;                 // first 256 B: done counter
    auto alloc = [&](size_t bytes) {
        void* p = ws + off;
        off += (bytes + 255) & ~size_t(255);
        return p;
    };
    const size_t PE = (size_t)C_CLS * D_DIM * K_MIX;
    int*    done     = (int*)ws;
    float2* abT      = (float2*)alloc(PE * sizeof(float2));
    float*  loT      = (float*) alloc(PE * sizeof(float));
    float*  upT      = (float*) alloc(PE * sizeof(float));
    float*  Ack      = (float*) alloc(C_CLS * K_MIX * sizeof(float));
    float*  const_ck = (float*) alloc(C_CLS * K_MIX * sizeof(float));
    int*    blockCnt = (int*)   alloc(HB * C_CLS * sizeof(int));
    int*    idxSorted= (int*)   alloc(N_PTS * sizeof(int));
    int*    classOff = (int*)   alloc((C_CLS + 1) * sizeof(int));
    float*  invden   = (float*) alloc(C_CLS * sizeof(float));
    float*  partials = (float*) alloc(GRID3 * sizeof(float));

    k_prep<<<C_CLS * K_MIX + HB, 256, 0, stream>>>(
        mu, lower, upper, sigma, y, abT, loT, upT, Ack, blockCnt);
    k_scatter<<<HB, 256, 0, stream>>>(
        y, blockCnt, logits, Ack, idxSorted, classOff, invden, const_ck, done);
    k_main<<<GRID3, 256, 0, stream>>>(
        X, y, resp, abT, loT, upT, const_ck, invden, idxSorted, eta,
        partials, done, out);
}